// Round 1
// baseline (59.994 us; speedup 1.0000x reference)
//
#include <hip/hip_runtime.h>

#define S7 7
#define NCELL 49      // S*S
#define CH 30

__global__ __launch_bounds__(256) void yolo_loss_kernel(
    const float* __restrict__ pred,
    const float* __restrict__ lab,
    float* __restrict__ out,
    int total_cells, float inv_B)
{
    int g = blockIdx.x * blockDim.x + threadIdx.x;
    float contrib = 0.0f;

    if (g < total_cells) {
        int b    = g / NCELL;
        int cell = g - b * NCELL;
        const float* __restrict__ pb = pred + (size_t)b * (CH * NCELL) + cell;
        const float* __restrict__ lb = lab  + (size_t)b * (CH * NCELL) + cell;

        // load first 10 channels of both tensors (box1, conf1, box2, conf2)
        float p[10], l[10];
        #pragma unroll
        for (int c = 0; c < 10; ++c) {
            p[c] = pb[c * NCELL];
            l[c] = lb[c * NCELL];
        }
        // class SSE over channels 10..29
        float cls = 0.0f;
        #pragma unroll
        for (int c = 10; c < CH; ++c) {
            float d = pb[c * NCELL] - lb[c * NCELL];
            cls += d * d;
        }

        int   row = cell / S7;
        float mi = (float)row;
        float nj = (float)(cell - row * S7);
        const float invS = 1.0f / 7.0f;

        // xyxy for pred box1, pred box2, gt box
        float ax1, ay1, ax2, ay2;
        {
            float cx = (p[0] + mi) * invS, cy = (p[1] + nj) * invS;
            ax1 = cx - 0.5f * p[2]; ay1 = cy - 0.5f * p[3];
            ax2 = cx + 0.5f * p[2]; ay2 = cy + 0.5f * p[3];
        }
        float bx1, by1, bx2, by2;
        {
            float cx = (p[5] + mi) * invS, cy = (p[6] + nj) * invS;
            bx1 = cx - 0.5f * p[7]; by1 = cy - 0.5f * p[8];
            bx2 = cx + 0.5f * p[7]; by2 = cy + 0.5f * p[8];
        }
        float gx1, gy1, gx2, gy2;
        {
            float cx = (l[0] + mi) * invS, cy = (l[1] + nj) * invS;
            gx1 = cx - 0.5f * l[2]; gy1 = cy - 0.5f * l[3];
            gx2 = cx + 0.5f * l[2]; gy2 = cy + 0.5f * l[3];
        }

        // IoU(b1, gt)
        float iou1, iou2;
        {
            float ix1 = fmaxf(ax1, gx1), iy1 = fmaxf(ay1, gy1);
            float ix2 = fminf(ax2, gx2), iy2 = fminf(ay2, gy2);
            float inter = fmaxf(ix2 - ix1, 0.0f) * fmaxf(iy2 - iy1, 0.0f);
            float a1 = (ax2 - ax1) * (ay2 - ay1);
            float a2 = (gx2 - gx1) * (gy2 - gy1);
            float denom = a1 + a2 - inter;
            iou1 = (inter > 0.0f) ? inter / denom : 0.0f;
        }
        {
            float ix1 = fmaxf(bx1, gx1), iy1 = fmaxf(by1, gy1);
            float ix2 = fminf(bx2, gx2), iy2 = fminf(by2, gy2);
            float inter = fmaxf(ix2 - ix1, 0.0f) * fmaxf(iy2 - iy1, 0.0f);
            float a1 = (bx2 - bx1) * (by2 - by1);
            float a2 = (gx2 - gx1) * (gy2 - gy1);
            float denom = a1 + a2 - inter;
            iou2 = (inter > 0.0f) ? inter / denom : 0.0f;
        }

        bool resp1 = (iou1 >= iou2);

        float d0 = p[0] - l[0], d1 = p[1] - l[1];
        float s2 = __builtin_sqrtf(p[2]) - __builtin_sqrtf(l[2]);
        float s3 = __builtin_sqrtf(p[3]) - __builtin_sqrtf(l[3]);
        float coor1 = 5.0f * (d0 * d0 + d1 * d1 + s2 * s2 + s3 * s3);

        float e0 = p[5] - l[5], e1 = p[6] - l[6];
        float t2 = __builtin_sqrtf(p[7]) - __builtin_sqrtf(l[7]);
        float t3 = __builtin_sqrtf(p[8]) - __builtin_sqrtf(l[8]);
        float coor2 = 5.0f * (e0 * e0 + e1 * e1 + t2 * t2 + t3 * t3);

        float o1 = p[4] - iou1; o1 *= o1;
        float o2 = p[9] - iou2; o2 *= o2;

        float coor       = resp1 ? coor1 : coor2;
        float obj_conf   = resp1 ? o1 : o2;
        float noobj_resp = 0.5f * (resp1 ? o2 : o1);
        float noobj_cell = 0.5f * (p[4] * p[4] + p[9] * p[9]);

        bool obj = (l[4] == 1.0f);
        contrib = obj ? (coor + obj_conf + noobj_resp + cls) : noobj_cell;
    }

    // wave-64 reduction
    #pragma unroll
    for (int off = 32; off > 0; off >>= 1)
        contrib += __shfl_down(contrib, off, 64);

    __shared__ float wsum[4];
    int lane = threadIdx.x & 63;
    int wid  = threadIdx.x >> 6;
    if (lane == 0) wsum[wid] = contrib;
    __syncthreads();
    if (threadIdx.x == 0) {
        float bs = wsum[0] + wsum[1] + wsum[2] + wsum[3];
        atomicAdd(out, bs * inv_B);
    }
}

extern "C" void kernel_launch(void* const* d_in, const int* in_sizes, int n_in,
                              void* d_out, int out_size, void* d_ws, size_t ws_size,
                              hipStream_t stream) {
    const float* pred = (const float*)d_in[0];
    const float* lab  = (const float*)d_in[1];
    float* out = (float*)d_out;

    int B = in_sizes[0] / (CH * NCELL);
    int total_cells = B * NCELL;

    hipMemsetAsync(out, 0, sizeof(float), stream);

    int block = 256;
    int grid = (total_cells + block - 1) / block;
    yolo_loss_kernel<<<grid, block, 0, stream>>>(pred, lab, out, total_cells, 1.0f / (float)B);
}